// Round 11
// baseline (43.785 us; speedup 1.0000x reference)
//
#include <hip/hip_runtime.h>

// Problem constants (from reference setup_inputs)
#define BB 32     // batch
#define UU 1152   // input_units
#define NN 10     // num_units
#define CC 8      // input_channels
#define DD 16     // channels_per_unit
#define EPS 1e-8f
#define INV_LN2 1.44269504088896341f

// inputs : (B, C, U)        float32
// weights: (U, N, C, D)     float32
// out    : (B, N, U, C, D)  float32
//
// R11: fill-mimicking persistent grid-stride.
// Virtual block vb in [0, 23040) owns the 8 KB output slice starting at
// float offset vb*2048 (linear: vb = (b*NN+n)*72 + uc, slice stride 2048).
// Launch 2304 persistent blocks; block b' processes vb = j*2304 + b',
// j = 0..9. At each j the ~2048 resident blocks write ONE dense ~19 MB
// window; windows advance linearly -> the same moving-front pattern as the
// 6.9 TB/s harness fill. In-thread, the store of iteration j overlaps the
// compute of iteration j+1 (fire-and-forget stores + independent work).
// Launch count drops 10x. Math identical to R10 (folded iter0, base-2
// logits, folded squash, 8-wide lane split, one DPP step per reduction).

typedef float f32x4 __attribute__((ext_vector_type(4)));

__device__ __forceinline__ float rcp_fast(float x) { return __builtin_amdgcn_rcpf(x); }
__device__ __forceinline__ float rsq_fast(float x) { return __builtin_amdgcn_rsqf(x); }

#if __has_builtin(__builtin_amdgcn_exp2f)
__device__ __forceinline__ float exp2_fast(float x) { return __builtin_amdgcn_exp2f(x); }
#else
__device__ __forceinline__ float exp2_fast(float x) { return __expf(x * 0.6931471805599453f); }
#endif

// sum across a lane PAIR (lanes 2k, 2k+1): one DPP xor-1 step
__device__ __forceinline__ float pair_sum(float x) {
    float y = __int_as_float(
        __builtin_amdgcn_update_dpp(0, __float_as_int(x), 0xB1, 0xF, 0xF, true)); // [1,0,3,2]
    return x + y;
}

__device__ __forceinline__ float hsum4(f32x4 a) {
    return (a.x + a.y) + (a.z + a.w);
}

__device__ __forceinline__ f32x4 exp2_v4(f32x4 a) {
    f32x4 r;
    r.x = exp2_fast(a.x); r.y = exp2_fast(a.y);
    r.z = exp2_fast(a.z); r.w = exp2_fast(a.w);
    return r;
}

#define NBLOCKS 2304
#define NITER   10        // 23040 virtual blocks / 2304

__global__ __launch_bounds__(256) void caps_route_kernel(
    const float* __restrict__ inputs,
    const float* __restrict__ weights,
    float* __restrict__ out)
{
    int tid = threadIdx.x;
    int sub = tid & 1;              // low/high 8 elements of D
    int c   = (tid >> 1) & 7;
    int ul  = tid >> 4;             // 0..15 (u within the 16-u slice)

    #pragma unroll 1
    for (int j = 0; j < NITER; ++j) {
        int vb = j * NBLOCKS + blockIdx.x;   // linear slice id
        int uc = vb % 72;
        int bn = vb / 72;
        int n  = bn % NN;
        int b  = bn / NN;
        int u  = uc * 16 + ul;

        float v = inputs[(b * CC + c) * UU + u];

        const float* wp = weights + ((u * NN + n) * CC + c) * DD + sub * 8;
        f32x4 wa = *reinterpret_cast<const f32x4*>(wp);
        f32x4 wb = *reinterpret_cast<const f32x4*>(wp + 4);

        f32x4 pa = wa * v, pb = wb * v;
        f32x4 qa = pa * pa, qb = pb * pb;

        // ---- iter 0 (folded): softmax uniform; L = scale0*INV_LN2/16 * q ----
        float sq0 = pair_sum(hsum4(qa + qb)) * (1.0f / 256.0f);
        float kk = sq0 * rcp_fast(1.0f + sq0) * rsq_fast(sq0 + EPS)
                   * (INV_LN2 / 16.0f);
        f32x4 La = kk * qa, Lb = kk * qb;

        // ---- iter 1 (base-2 logit update via m = e*q) ----
        {
            f32x4 ea = exp2_v4(La), eb = exp2_v4(Lb);
            float S = pair_sum(hsum4(ea + eb));
            f32x4 ma = ea * qa, mb = eb * qb;
            float A = pair_sum(hsum4(ma * ea + mb * eb));
            float Ssq = S * S;
            float k = A * rsq_fast(fmaf(EPS, Ssq, A)) * rcp_fast(Ssq + A)
                      * INV_LN2;
            La += k * ma;  Lb += k * mb;
        }

        // ---- iter 2 (final; logit update dead) ----
        {
            f32x4 ea = exp2_v4(La), eb = exp2_v4(Lb);
            float S = pair_sum(hsum4(ea + eb));
            f32x4 ta = ea * pa, tb = eb * pb;
            float A = pair_sum(hsum4(ta * ta + tb * tb));
            float Ssq = S * S;
            float ko = A * rsq_fast(fmaf(EPS, Ssq, A)) * rcp_fast(Ssq + A);

            // slice base = vb*2048 floats; within slice: ul*128 + c*16 + sub*8
            float* op = out + (long long)vb * 2048 + ul * (CC * DD) + c * DD + sub * 8;
            *reinterpret_cast<f32x4*>(op)     = ko * ta;
            *reinterpret_cast<f32x4*>(op + 4) = ko * tb;
        }
    }
}

extern "C" void kernel_launch(void* const* d_in, const int* in_sizes, int n_in,
                              void* d_out, int out_size, void* d_ws, size_t ws_size,
                              hipStream_t stream) {
    const float* inputs  = (const float*)d_in[0];
    const float* weights = (const float*)d_in[1];
    float* out = (float*)d_out;

    caps_route_kernel<<<NBLOCKS, 256, 0, stream>>>(inputs, weights, out);
}